// Round 2
// baseline (186.701 us; speedup 1.0000x reference)
//
#include <hip/hip_runtime.h>
#include <cstdint>

#define B2 2
#define CCH 256
#define HH 64
#define WW 64
#define HWHW 4096
#define KOUT 324

// ---------------------------------------------------------------------------
// (B,C,H,W) -> (B,HW,C) channel-last transpose for both fmaps.
// grid (HW/32, C/32, 4), block (32,8). z<2 -> fmap1, z>=2 -> fmap2.
// ---------------------------------------------------------------------------
__global__ __launch_bounds__(256) void transpose_cl(
    const float* __restrict__ f1, const float* __restrict__ f2,
    float* __restrict__ f1t, float* __restrict__ f2t) {
  __shared__ float tile[32][33];
  int zz = blockIdx.z;
  const float* src = (zz < 2) ? f1 : f2;
  float* dst = (zz < 2) ? f1t : f2t;
  int b = zz & 1;
  int hw0 = blockIdx.x * 32;
  int c0 = blockIdx.y * 32;
  int tx = threadIdx.x;
  int ty = threadIdx.y;
  const float* sb = src + (size_t)b * CCH * HWHW;
  float* db = dst + (size_t)b * HWHW * CCH;
#pragma unroll
  for (int i = 0; i < 4; i++)
    tile[ty + i * 8][tx] = sb[(size_t)(c0 + ty + i * 8) * HWHW + hw0 + tx];
  __syncthreads();
#pragma unroll
  for (int i = 0; i < 4; i++)
    db[(size_t)(hw0 + ty + i * 8) * CCH + c0 + tx] = tile[tx][ty + i * 8];
}

// ---------------------------------------------------------------------------
// Build pyramid levels 1..3 directly from level 0 (direct 2^L x 2^L mean ==
// iterated 2x2 means up to fp rounding). Channel-last float4 over channels.
// ---------------------------------------------------------------------------
__global__ __launch_bounds__(256) void pool_all(
    const float4* __restrict__ l0, float4* __restrict__ l1,
    float4* __restrict__ l2, float4* __restrict__ l3) {
  int idx = blockIdx.x * blockDim.x + threadIdx.x;
  const int n1 = B2 * 32 * 32 * 64;
  const int n2 = B2 * 16 * 16 * 64;
  const int n3 = B2 * 8 * 8 * 64;
  int L, Wo, local;
  float4* dst;
  if (idx < n1) { L = 1; Wo = 32; local = idx; dst = l1; }
  else if (idx < n1 + n2) { L = 2; Wo = 16; local = idx - n1; dst = l2; }
  else if (idx < n1 + n2 + n3) { L = 3; Wo = 8; local = idx - n1 - n2; dst = l3; }
  else return;
  int f = 1 << L;
  int sh = 6 - L;                 // log2(Wo)
  int c4 = local & 63;
  int t = local >> 6;
  int x = t & (Wo - 1);
  int y = (t >> sh) & (Wo - 1);
  int b = t >> (2 * sh);
  const float4* src = l0 + ((size_t)b * HH * WW) * 64 + c4;
  float4 acc = make_float4(0.f, 0.f, 0.f, 0.f);
  for (int dy = 0; dy < f; dy++)
    for (int dx = 0; dx < f; dx++) {
      float4 a = src[(size_t)((y * f + dy) * WW + (x * f + dx)) * 64];
      acc.x += a.x; acc.y += a.y; acc.z += a.z; acc.w += a.w;
    }
  float s = 1.0f / (float)(f * f);
  acc.x *= s; acc.y *= s; acc.z *= s; acc.w *= s;
  dst[local] = acc;
}

// ---------------------------------------------------------------------------
// Main: one block per query, wave = pyramid level, XCD-contiguous swizzle.
// Within a wave: 4 taps in flight (lane>>4), 16 lanes per tap each owning
// 16 channels. Results go to pout (n, 324) fully contiguous per query.
// ---------------------------------------------------------------------------
__global__ __launch_bounds__(256) void sample_k(
    const float* __restrict__ coords,
    const float* __restrict__ f1t,
    const float* __restrict__ f2l0, const float* __restrict__ f2l1,
    const float* __restrict__ f2l2, const float* __restrict__ f2l3,
    float* __restrict__ pout) {
  __shared__ float4 f1s[64];
  __shared__ float P[4][100];
  int bid = blockIdx.x;
  int n = ((bid & 7) << 10) | (bid >> 3);  // XCD-contiguous chunks (8192 % 8 == 0)
  int b = n >> 12;
  int i = n & 4095;
  int yi = i >> 6, xi = i & 63;
  int tid = threadIdx.x;
  if (tid < 64) f1s[tid] = ((const float4*)(f1t + (size_t)n * CCH))[tid];
  float clx = coords[((size_t)(b * 2 + 0) * HH + yi) * WW + xi];
  float cly = coords[((size_t)(b * 2 + 1) * HH + yi) * WW + xi];
  __syncthreads();

  int l = tid >> 6;    // wave index = level
  int lane = tid & 63;
  int lg = lane >> 4;  // which of 4 concurrent taps
  int l16 = lane & 15; // channel-group lane within tap

  float inv = 1.0f / (float)(1 << l);
  float xl = clx * inv, yl = cly * inv;
  float fx = floorf(xl), fy = floorf(yl);
  int ix0 = (int)fx - 4, iy0 = (int)fy - 4;
  float wx1 = xl - fx, wx0 = 1.0f - wx1;
  float wy1 = yl - fy, wy0 = 1.0f - wy1;
  int Hl = HH >> l, Wl = WW >> l;
  const float* f2 = (l == 0) ? f2l0 : (l == 1) ? f2l1 : (l == 2) ? f2l2 : f2l3;
  const float4* f2b = (const float4*)(f2) + (size_t)b * Hl * Wl * 64 + l16;

  float4 f1c0 = f1s[l16];
  float4 f1c1 = f1s[16 + l16];
  float4 f1c2 = f1s[32 + l16];
  float4 f1c3 = f1s[48 + l16];

  // taps t = it*4 + lg; u = t/10 (x index), v = t%10 (y index), incremental
  int u = 0, v = lg, t = lg;
  for (int it = 0; it < 25; it++) {
    int txp = ix0 + u, typ = iy0 + v;
    float partial = 0.0f;
    if (((unsigned)txp < (unsigned)Wl) && ((unsigned)typ < (unsigned)Hl)) {
      const float4* tp = f2b + (size_t)(typ * Wl + txp) * 64;
      float4 a0 = tp[0];
      float4 a1 = tp[16];
      float4 a2 = tp[32];
      float4 a3 = tp[48];
      partial = a0.x * f1c0.x + a0.y * f1c0.y + a0.z * f1c0.z + a0.w * f1c0.w
              + a1.x * f1c1.x + a1.y * f1c1.y + a1.z * f1c1.z + a1.w * f1c1.w
              + a2.x * f1c2.x + a2.y * f1c2.y + a2.z * f1c2.z + a2.w * f1c2.w
              + a3.x * f1c3.x + a3.y * f1c3.y + a3.z * f1c3.z + a3.w * f1c3.w;
    }
    partial += __shfl_xor(partial, 8, 64);
    partial += __shfl_xor(partial, 4, 64);
    partial += __shfl_xor(partial, 2, 64);
    partial += __shfl_xor(partial, 1, 64);
    if (l16 == 0) P[l][t] = partial * 0.0625f;  // 1/sqrt(256)
    t += 4;
    v += 4;
    if (v >= 10) { v -= 10; u += 1; }
  }
  __syncthreads();

  float* po = pout + (size_t)n * KOUT + l * 81;
  {
    int k = lane;  // 0..63
    int a = k / 9, bb = k - a * 9;
    float val = wy0 * (wx0 * P[l][a * 10 + bb] + wx1 * P[l][(a + 1) * 10 + bb])
              + wy1 * (wx0 * P[l][a * 10 + bb + 1] + wx1 * P[l][(a + 1) * 10 + bb + 1]);
    po[k] = val;
  }
  if (lane < 17) {
    int k = lane + 64;
    int a = k / 9, bb = k - a * 9;
    float val = wy0 * (wx0 * P[l][a * 10 + bb] + wx1 * P[l][(a + 1) * 10 + bb])
              + wy1 * (wx0 * P[l][a * 10 + bb + 1] + wx1 * P[l][(a + 1) * 10 + bb + 1]);
    po[k] = val;
  }
}

// ---------------------------------------------------------------------------
// (B, HW, 324) -> (B, 324, HW) tiled transpose, fully coalesced both sides.
// ---------------------------------------------------------------------------
__global__ __launch_bounds__(256) void writeout(
    const float* __restrict__ pout, float* __restrict__ out) {
  __shared__ float tile[32][33];
  int b = blockIdx.z;
  int hw0 = blockIdx.x * 32;
  int ch0 = blockIdx.y * 32;
  int tx = threadIdx.x, ty = threadIdx.y;
  const float* pb = pout + (size_t)b * HWHW * KOUT;
  float* ob = out + (size_t)b * KOUT * HWHW;
  if (ch0 + tx < KOUT) {
#pragma unroll
    for (int i = 0; i < 4; i++)
      tile[ty + i * 8][tx] = pb[(size_t)(hw0 + ty + i * 8) * KOUT + ch0 + tx];
  }
  __syncthreads();
#pragma unroll
  for (int i = 0; i < 4; i++) {
    int ch = ch0 + ty + i * 8;
    if (ch < KOUT)
      ob[(size_t)ch * HWHW + hw0 + tx] = tile[tx][ty + i * 8];
  }
}

// ---------------------------------------------------------------------------
extern "C" void kernel_launch(void* const* d_in, const int* in_sizes, int n_in,
                              void* d_out, int out_size, void* d_ws, size_t ws_size,
                              hipStream_t stream) {
  const float* fmap1 = (const float*)d_in[0];
  const float* fmap2 = (const float*)d_in[1];
  const float* coords = (const float*)d_in[2];
  float* out = (float*)d_out;

  char* ws = (char*)d_ws;
  float* f1t  = (float*)(ws);                        // 8 MB   (B,HW,C)
  float* f2l0 = (float*)(ws + ((size_t)8 << 20));    // 8 MB   (B,64,64,C)
  float* f2l1 = (float*)(ws + ((size_t)16 << 20));   // 2 MB   (B,32,32,C)
  float* f2l2 = (float*)(ws + ((size_t)18 << 20));   // 512 KB (B,16,16,C)
  float* f2l3 = (float*)(ws + ((size_t)19 << 20));   // 128 KB (B,8,8,C)
  float* pout = (float*)(ws + ((size_t)20 << 20));   // 10.6MB (B*HW, 324)

  dim3 tb(32, 8, 1);
  dim3 tg(HWHW / 32, CCH / 32, 4);
  transpose_cl<<<tg, tb, 0, stream>>>(fmap1, fmap2, f1t, f2l0);

  int npool = B2 * (32 * 32 + 16 * 16 + 8 * 8) * 64;
  pool_all<<<(npool + 255) / 256, 256, 0, stream>>>(
      (const float4*)f2l0, (float4*)f2l1, (float4*)f2l2, (float4*)f2l3);

  sample_k<<<HWHW * B2, 256, 0, stream>>>(coords, f1t, f2l0, f2l1, f2l2, f2l3, pout);

  dim3 wb(32, 8, 1);
  dim3 wg(HWHW / 32, (KOUT + 31) / 32, B2);
  writeout<<<wg, wb, 0, stream>>>(pout, out);
}